// Round 15
// baseline (110.897 us; speedup 1.0000x reference)
//
#include <hip/hip_runtime.h>

// ConvTranspose3d (2,64,32^3) fp32 -> (2,32,66^3), stride2 pad1 outpad1 dil2 k3.
// Odd-grid MFMA: out[n,co,2dp+1,2hp+1,2wp+1] = bias[co] +
//   sum_{ci,kd,kh,kw} x[n,ci,dp+1-kd,hp+1-kh,wp+1-kw] * w[ci,co,kd,kh,kw]
// R15 (= R14 + compile fix): no x16 intermediate. wprep packs weights only.
// conv stages x fp32 -> f16 LDS in-kernel (coalesced 8-plane loads -> b128,
// linear ccg layout = R13's proven conflict-free K-loop reads), MFMAs, and
// writes EVERYTHING: odd-od planes + 2.125 even-od bias planes per block (NT).

#define DOUT 66
#define PL (DOUT*DOUT)                  // 4356 floats/plane

typedef _Float16 half8 __attribute__((ext_vector_type(8)));
typedef float    floatx16 __attribute__((ext_vector_type(16)));
typedef float    floatx4  __attribute__((ext_vector_type(4)));

#define ROW_B 4352                      // LDS row: 8ccg * 34iwl * 8ci8 * 2B

// ---- k1: wprep = wA[cc 4][tap 27][lane 64][8 f16]; lane=co+32*khalf ----
__global__ void __launch_bounds__(256) wprep(const float* __restrict__ w,
                                             _Float16* __restrict__ wA) {
    int o = blockIdx.x * 256 + threadIdx.x;          // < 55296
    if (o >= 55296) return;
    int j = o & 7;
    int tmp = o >> 3;
    int lane = tmp & 63;
    int g = tmp >> 6;                    // cc*27 + tap
    int cc = g / 27, tap = g - cc * 27;
    int co = lane & 31, khalf = lane >> 5;
    int ci = cc * 16 + khalf * 8 + j;
    wA[o] = (_Float16)w[ci * 864 + co * 27 + tap];
}

// ---- k2: conv — 2hp blocks, 3/CU, in-kernel staging, split-K, all stores ----
__global__ void __launch_bounds__(256, 3) convt(
    const float* __restrict__ x, const _Float16* __restrict__ wA,
    const float* __restrict__ bias, float* __restrict__ out)
{
    __shared__ __align__(16) unsigned char xlds[52224];   // 12 rows x 4352 B

    const int tid  = threadIdx.x;
    const int lane = tid & 63;
    const int wv   = tid >> 6;           // wave = K chunk (16 ci)

    const unsigned b = blockIdx.x;       // 1024: xcd(3) | dp(5) | hq2(2)
    const unsigned xcd = b & 7u;
    const int n   = xcd & 1;
    const unsigned rest = b >> 3;
    const int dp  = rest & 31;
    const int hq2 = rest >> 5;           // 0..3
    const int hpg = (int)((xcd >> 1) * 4 + hq2);   // 0..15
    const int hpb = hpg * 2;             // hp0 = hpb, hp1 = hpb+1

    // ---- A: 27 uint4 batch load (oldest in flight; drains at barrier) ----
    uint4 A[27];
    const _Float16* wl = wA + ((size_t)wv * 27 * 64 + lane) * 8;
    #pragma unroll
    for (int t = 0; t < 27; ++t) A[t] = *(const uint4*)(wl + t * 512);

    // ---- stage x: thread (iw=tid&31, G=tid>>5): 8 plane loads -> b128 ----
    // layout: xlds[row][ccg=G][iwl=iw+1][ci8] (linear; K-loop reads proven 0-conflict)
    {
        const float* xg = x + (size_t)n * 2097152 + (size_t)(8 * (tid >> 5)) * 32768
                          + (tid & 31);
        const int iw = tid & 31;
        const int G  = tid >> 5;
        #pragma unroll
        for (int r = 0; r < 12; ++r) {
            const int idl = r >> 2, ihl = r & 3;
            const int id = dp - 1 + idl, ih = hpb - 1 + ihl;
            uint4 pk = make_uint4(0u, 0u, 0u, 0u);
            if (((unsigned)id < 32u) & ((unsigned)ih < 32u)) {
                const float* xr = xg + (id * 32 + ih) * 32;
                float f[8];
                #pragma unroll
                for (int j = 0; j < 8; ++j) f[j] = xr[(size_t)j * 32768];
                pk.x = __builtin_bit_cast(unsigned, __builtin_amdgcn_cvt_pkrtz(f[0], f[1]));
                pk.y = __builtin_bit_cast(unsigned, __builtin_amdgcn_cvt_pkrtz(f[2], f[3]));
                pk.z = __builtin_bit_cast(unsigned, __builtin_amdgcn_cvt_pkrtz(f[4], f[5]));
                pk.w = __builtin_bit_cast(unsigned, __builtin_amdgcn_cvt_pkrtz(f[6], f[7]));
            }
            *(uint4*)&xlds[r * ROW_B + G * 544 + (iw + 1) * 16] = pk;
        }
        // halo columns iwl = 0, 33: 12 rows x 8 ccg x 2 sides
        if (tid < 192) {
            const int row = tid >> 4;
            const int rem = tid & 15;
            const int ccg = rem >> 1, side = rem & 1;
            *(uint4*)&xlds[row * ROW_B + ccg * 544 + (side ? 33 : 0) * 16] =
                make_uint4(0u, 0u, 0u, 0u);
        }
    }
    __syncthreads();

    // ---- K-loop: 54 MFMAs (27 taps x 2 hp tiles), pure ds_read_b128 ----
    const int wp    = lane & 31;
    const int khalf = lane >> 5;
    const int cbase = (2 * wv + khalf) * 544 + wp * 16;

    floatx16 acc0 = {}, acc1 = {};
    #pragma unroll
    for (int kd = 0; kd < 3; ++kd)
    #pragma unroll
    for (int kh = 0; kh < 3; ++kh)
    #pragma unroll
    for (int kw = 0; kw < 3; ++kw) {
        const int tap = (kd * 3 + kh) * 3 + kw;
        const int row0 = (2 - kd) * 4 + (2 - kh);   // tile0; tile1 = row0+1
        const uint4* bp0 = (const uint4*)(xlds + row0 * ROW_B + cbase + (2 - kw) * 16);
        acc0 = __builtin_amdgcn_mfma_f32_32x32x16_f16(
            __builtin_bit_cast(half8, A[tap]),
            __builtin_bit_cast(half8, bp0[0]), acc0, 0, 0, 0);
        const uint4* bp1 = (const uint4*)((const char*)bp0 + ROW_B);
        acc1 = __builtin_amdgcn_mfma_f32_32x32x16_f16(
            __builtin_bit_cast(half8, A[tap]),
            __builtin_bit_cast(half8, bp1[0]), acc1, 0, 0, 0);
    }

    // ---- distributed split-K reduce: wave0 finalizes tile0, wave1 tile1 ----
    __syncthreads();
    float* part = (float*)xlds;          // part[(w*2+t)*16 + r][lane]
    if (wv != 0) {
        #pragma unroll
        for (int r = 0; r < 16; ++r)
            part[((wv * 2 + 0) * 16 + r) * 64 + lane] = acc0[r];
    }
    if (wv != 1) {
        #pragma unroll
        for (int r = 0; r < 16; ++r)
            part[((wv * 2 + 1) * 16 + r) * 64 + lane] = acc1[r];
    }
    __syncthreads();

    const int od = 2 * dp + 1;
    if (wv <= 1) {
        float s[16];
        #pragma unroll
        for (int r = 0; r < 16; ++r) {
            s[r] = (wv == 0) ? acc0[r] : acc1[r];
            #pragma unroll
            for (int w2 = 0; w2 < 4; ++w2) {
                if (w2 == wv) continue;
                s[r] += part[((w2 * 2 + wv) * 16 + r) * 64 + lane];
            }
        }
        const int oh = 2 * (hpb + wv) + 1;           // conv row
        #pragma unroll
        for (int r = 0; r < 16; ++r) {
            const int co = (r & 3) + 8 * (r >> 2) + 4 * khalf;   // verified C/D map
            const float bv = bias[co];
            float2* orow = (float2*)(out +
                ((size_t)(n * 32 + co) * DOUT + od) * PL + oh * DOUT);
            orow[wp] = make_float2(bv, s[r] + bv);
            if (wp == 31) orow[32] = make_float2(bv, bv);
        }
    } else {
        // even bias rows of this odd-od plane: wv2 -> 2hpb, wv3 -> 2hpb+2;
        // tails oh 64/65 at hpg15
        const int oh = (wv == 2) ? 2 * hpb : 2 * hpb + 2;
        const int oht = (wv == 2) ? 64 : 65;
        const bool tails = (hpg == 15);
        #pragma unroll
        for (int r = 0; r < 16; ++r) {
            const int co = (r & 3) + 8 * (r >> 2) + 4 * khalf;
            const float bv = bias[co];
            float* pbase = out + ((size_t)(n * 32 + co) * DOUT + od) * PL;
            float2* erow = (float2*)(pbase + oh * DOUT);
            erow[wp] = make_float2(bv, bv);
            if (wp == 31) erow[32] = make_float2(bv, bv);
            if (tails) {
                float2* trow = (float2*)(pbase + oht * DOUT);
                trow[wp] = make_float2(bv, bv);
                if (wp == 31) trow[32] = make_float2(bv, bv);
            }
        }
    }

    // ---- bias planes (od even + od=65): 2176 planes over 1024 blocks ----
    // block b owns planes {b, b+1024, 2048+b if b<128}; 1089 float4 each, NT.
    #pragma unroll
    for (int k = 0; k < 3; ++k) {
        unsigned p;
        if (k == 0)      p = b;
        else if (k == 1) p = b + 1024u;
        else { if (b >= 128u) break; p = 2048u + b; }
        const unsigned nc = p / 34u, e = p - nc * 34u;
        const unsigned odp = (e < 33u) ? 2u * e : 65u;
        const float v = bias[nc & 31u];
        const floatx4 v4 = {v, v, v, v};
        floatx4* pb = (floatx4*)(out + ((size_t)nc * DOUT + odp) * PL);
        #pragma unroll
        for (int j = 0; j < 5; ++j) {
            const unsigned idx = j * 256u + tid;
            if (idx < 1089u) __builtin_nontemporal_store(v4, pb + idx);
        }
    }
}

extern "C" void kernel_launch(void* const* d_in, const int* in_sizes, int n_in,
                              void* d_out, int out_size, void* d_ws, size_t ws_size,
                              hipStream_t stream) {
    const float* x    = (const float*)d_in[0];
    const float* wgt  = (const float*)d_in[1];
    const float* bias = (const float*)d_in[2];
    float* out = (float*)d_out;
    _Float16* wA = (_Float16*)d_ws;                  // 110,592 B

    wprep<<<216, 256, 0, stream>>>(wgt, wA);
    convt<<<1024, 256, 0, stream>>>(x, wA, bias, out);
}